// Round 3
// baseline (51.551 us; speedup 1.0000x reference)
//
#include <hip/hip_runtime.h>

// TopologicalLoss: loss = mean(([1,0]-target)^2); grad[b,l,c] = mask[b,l] ? (per_b[b]-loss)/eps : 0
// B=8, L=1024, C=8192. Output: [loss, grad(flat)] = 67,108,865 f32 = 268.4 MB pure stores.
// Single fused kernel: per-block recompute of loss/diff into LDS + NT float4 stores.

#define B_DIM 8
#define L_DIM 1024
#define C_DIM 8192
#define NROWS (B_DIM * L_DIM)   // 8192
#define EPS_INV 1000.0f

// Native clang vector: __builtin_nontemporal_store requires a vector of
// scalar types, not HIP's HIP_vector_type<float,4> class.
typedef float f32x4 __attribute__((ext_vector_type(4)));

// out[0] = loss; out[1 + g] = grad[g], g in [0, B*L*C).
// Chunk m covers out[4m .. 4m+3]:
//   m == 0: {loss, grad[0], grad[1], grad[2]}
//   m >= 1: {grad[4m-1], grad[4m], grad[4m+1], grad[4m+2]}
// grad indices 4m..4m+2 share a row (row = g>>13 changes only at multiples of
// 8192 == 0 mod 4); grad[4m-1] may belong to the previous row.
__global__ void topo_fused(const void* __restrict__ mask_raw,
                           const float* __restrict__ target,
                           float* __restrict__ out,
                           long long M)
{
    __shared__ float s_diff[9];   // [0..7] = diff per batch, [8] = loss

    if (threadIdx.x == 0) {
        float pb0, pb1, pb2, pb3, pb4, pb5, pb6, pb7;
        float loss = 0.0f;
        // per_b[b] = 0.5*((1-t0)^2 + t1^2); loss = mean over all 16 = sum(per_b)/8
        {
            float t0, t1, e0;
#define PB(i, dst) t0 = target[2*(i)]; t1 = target[2*(i)+1]; e0 = 1.0f - t0; \
                   dst = 0.5f * (e0*e0 + t1*t1); loss += dst;
            PB(0, pb0) PB(1, pb1) PB(2, pb2) PB(3, pb3)
            PB(4, pb4) PB(5, pb5) PB(6, pb6) PB(7, pb7)
#undef PB
        }
        loss *= (1.0f / 8.0f);
        s_diff[0] = (pb0 - loss) * EPS_INV;
        s_diff[1] = (pb1 - loss) * EPS_INV;
        s_diff[2] = (pb2 - loss) * EPS_INV;
        s_diff[3] = (pb3 - loss) * EPS_INV;
        s_diff[4] = (pb4 - loss) * EPS_INV;
        s_diff[5] = (pb5 - loss) * EPS_INV;
        s_diff[6] = (pb6 - loss) * EPS_INV;
        s_diff[7] = (pb7 - loss) * EPS_INV;
        s_diff[8] = loss;
    }

    // Mask storage detection (verified absmax=0 in R1):
    // int32 0/1 words have upper 3 bytes zero in the first 128 bytes;
    // 1-byte bools (random 0/1) put a nonzero byte at offset %4 != 0
    // with prob 1 - 2^-96. All threads compute it redundantly (L1 hits).
    const unsigned int* mw = (const unsigned int*)mask_raw;
    bool byte_mode = false;
#pragma unroll
    for (int i = 0; i < 32; ++i) {
        if (mw[i] & 0xFFFFFF00u) byte_mode = true;
    }
    const unsigned char* mb = (const unsigned char*)mask_raw;
    const int*           mi = (const int*)mask_raw;

    __syncthreads();

    long long stride = (long long)gridDim.x * blockDim.x;
    for (long long m = (long long)blockIdx.x * blockDim.x + threadIdx.x;
         m < M; m += stride) {
        long long g = m << 2;                       // grad index of lane .y
        int row = (int)(g >> 13);
        int mval = byte_mode ? (int)mb[row] : mi[row];
        float val = mval ? s_diff[row >> 10] : 0.0f;

        float vx = val;
        if ((g & (C_DIM - 1)) == 0) {               // row-start chunk
            if (m == 0) {
                vx = s_diff[8];                     // loss scalar
            } else {
                int prow = row - 1;
                int pmval = byte_mode ? (int)mb[prow] : mi[prow];
                vx = pmval ? s_diff[prow >> 10] : 0.0f;
            }
        }

        f32x4 v = {vx, val, val, val};
        __builtin_nontemporal_store(v, reinterpret_cast<f32x4*>(out + g));

        if (m == M - 1) {                           // final grad element
            int lrow = NROWS - 1;
            int lmval = byte_mode ? (int)mb[lrow] : mi[lrow];
            out[M << 2] = lmval ? s_diff[7] : 0.0f;
        }
    }
}

extern "C" void kernel_launch(void* const* d_in, const int* in_sizes, int n_in,
                              void* d_out, int out_size, void* d_ws, size_t ws_size,
                              hipStream_t stream) {
    // d_in[0] = logits (unused), d_in[1] = mask (8192 bool/int), d_in[2] = target (16 f32)
    const void*  mask   = d_in[1];
    const float* target = (const float*)d_in[2];
    float* out = (float*)d_out;

    long long M = ((long long)out_size - 1) >> 2;   // 16,777,216 float4 chunks

    // 2048 blocks x 256 threads = 8192 waves = exactly 32 waves/CU; 32 chunks/thread.
    topo_fused<<<2048, 256, 0, stream>>>(mask, target, out, M);
}

// Round 4
// 42.174 us; speedup vs baseline: 1.2224x; 1.2224x over previous
//
#include <hip/hip_runtime.h>

// TopologicalLoss: loss = mean(([1,0]-target)^2); grad[b,l,c] = mask[b,l] ? (per_b[b]-loss)/eps : 0
// B=8, L=1024, C=8192. Output: [loss, grad(flat)] = 67,108,865 f32 = 268.4 MB pure stores.
// Single fused kernel; PLAIN float4 stores (R3 showed nontemporal stores cost ~10%
// vs the regular L2-write-back path that fillBufferAligned uses at 7.0 TB/s).

#define B_DIM 8
#define L_DIM 1024
#define C_DIM 8192
#define NROWS (B_DIM * L_DIM)   // 8192
#define EPS_INV 1000.0f

// out[0] = loss; out[1 + g] = grad[g], g in [0, B*L*C).
// Chunk m covers out[4m .. 4m+3]:
//   m == 0: {loss, grad[0], grad[1], grad[2]}
//   m >= 1: {grad[4m-1], grad[4m], grad[4m+1], grad[4m+2]}
// grad indices 4m..4m+2 share a row (row = g>>13 changes only at multiples of
// 8192 == 0 mod 4); grad[4m-1] may belong to the previous row.
__global__ void topo_fused(const void* __restrict__ mask_raw,
                           const float* __restrict__ target,
                           float* __restrict__ out,
                           long long M)
{
    __shared__ float s_diff[9];   // [0..7] = diff per batch, [8] = loss

    if (threadIdx.x == 0) {
        float pb0, pb1, pb2, pb3, pb4, pb5, pb6, pb7;
        float loss = 0.0f;
        // per_b[b] = 0.5*((1-t0)^2 + t1^2); loss = mean over all 16 = sum(per_b)/8
        {
            float t0, t1, e0;
#define PB(i, dst) t0 = target[2*(i)]; t1 = target[2*(i)+1]; e0 = 1.0f - t0; \
                   dst = 0.5f * (e0*e0 + t1*t1); loss += dst;
            PB(0, pb0) PB(1, pb1) PB(2, pb2) PB(3, pb3)
            PB(4, pb4) PB(5, pb5) PB(6, pb6) PB(7, pb7)
#undef PB
        }
        loss *= (1.0f / 8.0f);
        s_diff[0] = (pb0 - loss) * EPS_INV;
        s_diff[1] = (pb1 - loss) * EPS_INV;
        s_diff[2] = (pb2 - loss) * EPS_INV;
        s_diff[3] = (pb3 - loss) * EPS_INV;
        s_diff[4] = (pb4 - loss) * EPS_INV;
        s_diff[5] = (pb5 - loss) * EPS_INV;
        s_diff[6] = (pb6 - loss) * EPS_INV;
        s_diff[7] = (pb7 - loss) * EPS_INV;
        s_diff[8] = loss;
    }

    // Mask storage detection (verified absmax=0 in R1/R3):
    // int32 0/1 words have upper 3 bytes zero in the first 128 bytes;
    // 1-byte bools (random 0/1) put a nonzero byte at offset %4 != 0
    // with prob 1 - 2^-96. All threads compute it redundantly (L1 hits).
    const unsigned int* mw = (const unsigned int*)mask_raw;
    bool byte_mode = false;
#pragma unroll
    for (int i = 0; i < 32; ++i) {
        if (mw[i] & 0xFFFFFF00u) byte_mode = true;
    }
    const unsigned char* mb = (const unsigned char*)mask_raw;
    const int*           mi = (const int*)mask_raw;

    __syncthreads();

    long long stride = (long long)gridDim.x * blockDim.x;
    for (long long m = (long long)blockIdx.x * blockDim.x + threadIdx.x;
         m < M; m += stride) {
        long long g = m << 2;                       // grad index of lane .y
        int row = (int)(g >> 13);
        int mval = byte_mode ? (int)mb[row] : mi[row];
        float val = mval ? s_diff[row >> 10] : 0.0f;

        float vx = val;
        if ((g & (C_DIM - 1)) == 0) {               // row-start chunk
            if (m == 0) {
                vx = s_diff[8];                     // loss scalar
            } else {
                int prow = row - 1;
                int pmval = byte_mode ? (int)mb[prow] : mi[prow];
                vx = pmval ? s_diff[prow >> 10] : 0.0f;
            }
        }

        float4 v = make_float4(vx, val, val, val);
        *reinterpret_cast<float4*>(out + g) = v;

        if (m == M - 1) {                           // final grad element
            int lrow = NROWS - 1;
            int lmval = byte_mode ? (int)mb[lrow] : mi[lrow];
            out[M << 2] = lmval ? s_diff[7] : 0.0f;
        }
    }
}

extern "C" void kernel_launch(void* const* d_in, const int* in_sizes, int n_in,
                              void* d_out, int out_size, void* d_ws, size_t ws_size,
                              hipStream_t stream) {
    // d_in[0] = logits (unused), d_in[1] = mask (8192 bool/int), d_in[2] = target (16 f32)
    const void*  mask   = d_in[1];
    const float* target = (const float*)d_in[2];
    float* out = (float*)d_out;

    long long M = ((long long)out_size - 1) >> 2;   // 16,777,216 float4 chunks

    // 4096 blocks x 256 threads (R1's store geometry); 16 chunks/thread grid-stride.
    topo_fused<<<4096, 256, 0, stream>>>(mask, target, out, M);
}

// Round 5
// 41.392 us; speedup vs baseline: 1.2454x; 1.0189x over previous
//
#include <hip/hip_runtime.h>

// TopologicalLoss: loss = mean(([1,0]-target)^2); grad[b,l,c] = mask[b,l] ? (per_b[b]-loss)/eps : 0
// B=8, L=1024, C=8192. Output: [loss, grad(flat)] = 67,108,865 f32 = 268.4 MB pure stores.
// R5: block-contiguous rows — each block owns 2 rows (4096 float4 chunks), mask
// hoisted to 3 scalar loads/block, inner loop = 16 unrolled dwordx4 stores
// (structurally the fillBufferAligned pattern that hits 7.0 TB/s).

#define B_DIM 8
#define L_DIM 1024
#define C_DIM 8192
#define NROWS 8192
#define EPS_INV 1000.0f
#define CHUNKS_PER_ROW 2048   // 8192 / 4
#define BLOCKS 4096           // NROWS / 2
#define TPB 256

__device__ __forceinline__ float per_b_val(const float* __restrict__ target, int i) {
    float t0 = target[2 * i], t1 = target[2 * i + 1];
    float e0 = 1.0f - t0;
    return 0.5f * (e0 * e0 + t1 * t1);
}

// out[0] = loss; out[1+g] = grad[g]. Chunk m covers out[4m..4m+3]:
//   m == 0        : {loss, grad[0..2]}
//   m % 2048 == 0 : .x = grad[4m-1] (last element of PREVIOUS row)
//   else          : all four from row m/2048.
// Block b owns chunks [b*4096, (b+1)*4096) = rows 2b and 2b+1 exactly.
// Iterations 0-7 are row 2b, 8-15 are row 2b+1 (row uniform per iteration).
__global__ void __launch_bounds__(TPB)
topo_fill2(const void* __restrict__ mask_raw,
           const float* __restrict__ target,
           float* __restrict__ out)
{
    int b = blockIdx.x;
    int t = threadIdx.x;
    int r0 = 2 * b, r1 = r0 + 1;

    // loss = mean of 8 per_b values
    float loss = 0.0f;
#pragma unroll
    for (int i = 0; i < 8; ++i) loss += per_b_val(target, i);
    loss *= 0.125f;

    // rows 2b and 2b+1 always share a batch (differ only in bit 0; >>10 equal)
    int bidx = r0 >> 10;
    float diff0 = (per_b_val(target, bidx) - loss) * EPS_INV;
    int prow = (r0 > 0) ? r0 - 1 : 0;
    float diffp = (per_b_val(target, prow >> 10) - loss) * EPS_INV;

    // Mask storage detection (verified absmax=0 in R1/R3/R4): int32 0/1 words
    // have upper 3 bytes zero in the first 128 bytes; 1-byte bools (random
    // 0/1) hit a nonzero byte at offset %4 != 0 with prob 1 - 2^-96.
    const unsigned int* mw = (const unsigned int*)mask_raw;
    bool byte_mode = false;
#pragma unroll
    for (int i = 0; i < 32; ++i) {
        if (mw[i] & 0xFFFFFF00u) byte_mode = true;
    }
    const unsigned char* mb = (const unsigned char*)mask_raw;
    const int*           mi = (const int*)mask_raw;

    int m0 = byte_mode ? (int)mb[r0]   : mi[r0];
    int m1 = byte_mode ? (int)mb[r1]   : mi[r1];
    int mp = byte_mode ? (int)mb[prow] : mi[prow];

    float val0 = m0 ? diff0 : 0.0f;
    float val1 = m1 ? diff0 : 0.0f;
    float valp = mp ? diffp : 0.0f;

    // Base chunk for this thread: b*4096 + t; iteration stride 256 chunks.
    float* p = out + (((long long)b * (2 * CHUNKS_PER_ROW) + t) << 2);

#pragma unroll
    for (int it = 0; it < 8; ++it) {          // row 2b
        float vx = val0;
        if (it == 0 && t == 0) vx = (b == 0) ? loss : valp;  // chunk m=b*4096
        float4 v = make_float4(vx, val0, val0, val0);
        *reinterpret_cast<float4*>(p + (long long)it * (TPB * 4)) = v;
    }
#pragma unroll
    for (int it = 8; it < 16; ++it) {         // row 2b+1
        float vx = val1;
        if (it == 8 && t == 0) vx = val0;     // boundary chunk: .x = last of row 2b
        float4 v = make_float4(vx, val1, val1, val1);
        *reinterpret_cast<float4*>(p + (long long)it * (TPB * 4)) = v;
    }

    // Final output element out[67108864] = grad[last] (row 8191 = r1 of block 4095)
    if (b == BLOCKS - 1 && t == TPB - 1) {
        out[(long long)NROWS * C_DIM] = val1;
    }
}

extern "C" void kernel_launch(void* const* d_in, const int* in_sizes, int n_in,
                              void* d_out, int out_size, void* d_ws, size_t ws_size,
                              hipStream_t stream) {
    // d_in[0] = logits (unused), d_in[1] = mask (8192 bool/int), d_in[2] = target (16 f32)
    const void*  mask   = d_in[1];
    const float* target = (const float*)d_in[2];
    float* out = (float*)d_out;

    topo_fill2<<<BLOCKS, TPB, 0, stream>>>(mask, target, out);
}